// Round 5
// baseline (396.731 us; speedup 1.0000x reference)
//
#include <hip/hip_runtime.h>

// ALSH conv setup: hash kernels, vote via 1-channel conv, histogram, argmax,
// gather active kernel set.
#define O_CH   256      // out_channels
#define C_CH   64       // in_channels
#define FLATK  576      // C*K*K
#define M_TERMS 9
#define AL     585      // D*K*K = (C + 1)*9
#define TSZ    8192     // table size
#define HSZ    1024     // compact LDS hist: |vote| is ~N(0,6) -> buckets 0..~40
#define RADIUS 4.0f
#define NB     16
#define HH     256
#define WW     256

// workspace layout (ints):
//   [0, 256)            k_idx : bucket of each kernel
//   [256, 256+8192)     hist  : vote histogram
//   [8448, 8450)        best  : 64-bit argmax key (count<<13 | (8191-idx))
#define WS_KIDX 0
#define WS_HIST 256
#define WS_BEST (256 + TSZ)

// ---------------- K1: hash kernels (1 wave per kernel) + zero histogram ----
__global__ __launch_bounds__(256) void k_init(const float* __restrict__ kernels,
                                              const float* __restrict__ a,
                                              const float* __restrict__ b,
                                              int* __restrict__ ws) {
    if (blockIdx.x < 64) {
        const int wv = threadIdx.x >> 6, lane = threadIdx.x & 63;
        const int o = blockIdx.x * 4 + wv;
        const float* wp = kernels + o * FLATK;
        float dot = 0.f, n2 = 0.f;
        #pragma unroll
        for (int j0 = 0; j0 < FLATK; j0 += 64) {   // 576/64 = 9 coalesced rounds
            float x = wp[j0 + lane];
            dot += x * a[j0 + lane];
            n2  += x * x;
        }
        #pragma unroll
        for (int off = 32; off > 0; off >>= 1) {
            dot += __shfl_xor(dot, off);
            n2  += __shfl_xor(n2, off);
        }
        if (lane == 0) {
            float p = n2, d = dot;
            for (int i = 0; i < M_TERMS; ++i) { d += p * a[FLATK + i]; p *= n2; }
            float hk = floorf((d + b[0]) / RADIUS);
            ws[WS_KIDX + o] = (int)fabsf(fmodf(hk, (float)TSZ));
        }
    } else {
        int t = (blockIdx.x - 64) * 256 + threadIdx.x;
        ws[WS_HIST + t] = 0;
        if (blockIdx.x == 64 && threadIdx.x < 2) ws[WS_BEST + threadIdx.x] = 0;
    }
}

// ---------------- K2: fused vote conv, half-row waves, 32 waves/CU --------
// Block: 512 threads = 8 waves; each wave owns HALF a row (128 px, 2 px/lane).
// Grid 1024 = 16 img x 32 ytiles x 2 xseg -> 4 blocks/CU = 32 waves/CU
// (latency-bound kernel: resident waves are the lever; VGPR<=64 required,
// measured cliff at 64->88). Compact 1024-entry LDS hist (4 KB) replaces the
// 32 KB one: |vote| concentrates near 0; >=HSZ falls back to global atomic.
// dist-2 prefetch via 3 named slots, manual 3x loop body so every buffer
// index is compile-time (runtime-indexed arrays spill to scratch).
// Segment-edge halo: one predicated scalar reg shared by lanes 0/63.
// Per-pixel FMA order (c -> ky -> kx per accumulator) unchanged -> bitwise
// identical votes.
#define TILE_H 8
__global__ __launch_bounds__(512, 4) void k_vote(const float* __restrict__ input,
                                                 const float* __restrict__ a,
                                                 const float* __restrict__ b,
                                                 int* __restrict__ ws) {
    __shared__ int   hist_s[HSZ];   // 4 KB
    __shared__ float a_s[AL];
    const int tid = threadIdx.x;

    for (int i = tid; i < HSZ; i += 512) hist_s[i] = 0;
    for (int i = tid; i < AL; i += 512) a_s[i] = a[i];
    __syncthreads();

    const float bv = b[0];
    int* hist_g = ws + WS_HIST;
    // swizzle: xcd = blockIdx&7 gets 128 consecutive tiles (2 whole images)
    const int t    = (blockIdx.x & 7) * 128 + (blockIdx.x >> 3);
    const int xs   = t & 1;                // x segment (0: cols 0-127, 1: 128-255)
    const int by   = (t >> 1) & 31;        // 32 row-tiles per image
    const int n    = t >> 6;               // 16 images
    const int lane = tid & 63;
    const int wv   = tid >> 6;             // 8 waves = 8 rows
    const int y    = by * TILE_H + wv;     // output row
    const int x2   = xs * 128 + lane * 2;  // columns x2, x2+1

    // halo: lane0 needs col x2-1, lane63 needs col x2+2 (disjoint lanes ->
    // share one register). Interior lanes get halo via shfl.
    const bool isE = (lane == 0) | (lane == 63);
    const int  hx  = (lane == 0) ? (x2 - 1) : (x2 + 2);
    const bool hok = isE && ((lane == 0) ? (x2 > 0) : (x2 + 2 < WW));

    float acc[2] = {0.f, 0.f};
    const float* imgbase = input + (size_t)n * C_CH * HH * WW;

    float2 v0[3], v1[3], v2[3];
    float  h0[3], h1[3], h2[3];

#define LOADCH(c, VB, HB)                                                     \
    if ((c) < C_CH) {                                                         \
        const float* src = imgbase + (size_t)(c) * (HH * WW);                 \
        _Pragma("unroll")                                                     \
        for (int r = 0; r < 3; ++r) {                                         \
            int gy = y - 1 + r;                                               \
            bool ok = (gy >= 0 && gy < HH);                                   \
            const float* rp = src + gy * WW;                                  \
            VB[r] = ok ? *(const float2*)(rp + x2) : make_float2(0.f, 0.f);   \
            HB[r] = (ok && hok) ? rp[hx] : 0.f;                               \
        }                                                                     \
    }

#define COMPCH(c, VB, HB)                                                     \
    {                                                                         \
        const float* ac = a_s + (c) * 9;                                      \
        _Pragma("unroll")                                                     \
        for (int r = 0; r < 3; ++r) {                                         \
            float2 v = VB[r];                                                 \
            float lv = __shfl_up(v.y, 1);                                     \
            float rv = __shfl_down(v.x, 1);                                   \
            if (lane == 0)  lv = HB[r];                                       \
            if (lane == 63) rv = HB[r];                                       \
            acc[0] += lv  * ac[r * 3 + 0];                                    \
            acc[0] += v.x * ac[r * 3 + 1];                                    \
            acc[0] += v.y * ac[r * 3 + 2];                                    \
            acc[1] += v.x * ac[r * 3 + 0];                                    \
            acc[1] += v.y * ac[r * 3 + 1];                                    \
            acc[1] += rv  * ac[r * 3 + 2];                                    \
        }                                                                     \
    }

    LOADCH(0, v0, h0)
    LOADCH(1, v1, h1)
    for (int c3 = 0; c3 < 63; c3 += 3) {   // channels 0..62; slot = c mod 3
        LOADCH(c3 + 2, v2, h2)
        COMPCH(c3 + 0, v0, h0)
        LOADCH(c3 + 3, v0, h0)
        COMPCH(c3 + 1, v1, h1)
        LOADCH(c3 + 4, v1, h1)
        COMPCH(c3 + 2, v2, h2)
    }
    COMPCH(63, v0, h0)                     // 63 mod 3 == 0
#undef LOADCH
#undef COMPCH

    // constant Q-channel (0.5 inside image, zero-padded) + vote
    #pragma unroll
    for (int p = 0; p < 2; ++p) {
        int gx = x2 + p;
        float cs = 0.f;
        #pragma unroll
        for (int ky = 0; ky < 3; ++ky) {
            int yy = y + ky - 1;
            if (yy < 0 || yy >= HH) continue;
            #pragma unroll
            for (int kx = 0; kx < 3; ++kx) {
                int xx = gx + kx - 1;
                if (xx < 0 || xx >= WW) continue;
                cs += a_s[FLATK + ky * 3 + kx];
            }
        }
        float tt = acc[p] + 0.5f * cs;
        float v = floorf((tt + bv) / RADIUS);
        int vi = (int)fabsf(fmodf(v, (float)TSZ));
        if (vi < HSZ) atomicAdd(&hist_s[vi], 1);
        else          atomicAdd(&hist_g[vi], 1);   // ~never taken
    }

    __syncthreads();
    for (int i = tid; i < HSZ; i += 512) {
        int v = hist_s[i];
        if (v) atomicAdd(&hist_g[i], v);
    }
}

// ---------------- K3: parallel argmax (32 blocks) + count output ----------
// key = count<<13 | (8191 - idx): max key => max count, tie => smallest idx
// (matches jnp.argmax first-occurrence semantics).
__global__ __launch_bounds__(256) void k_argmax(const int* __restrict__ ws,
                                                int* __restrict__ wsbest,
                                                float* __restrict__ out) {
    const int tid = threadIdx.x;
    const int t = blockIdx.x * 256 + tid;
    const int v = ws[WS_HIST + t];
    out[512 * FLATK + t] = (float)v;      // count output (coalesced)

    unsigned long long key =
        ((unsigned long long)(unsigned)v << 13) | (unsigned)(TSZ - 1 - t);
    #pragma unroll
    for (int off = 32; off > 0; off >>= 1) {
        unsigned long long o = __shfl_xor(key, off);
        if (o > key) key = o;
    }
    __shared__ unsigned long long wk[4];
    const int lane = tid & 63, wvi = tid >> 6;
    if (lane == 0) wk[wvi] = key;
    __syncthreads();
    if (tid == 0) {
        unsigned long long k = wk[0];
        for (int i = 1; i < 4; ++i) if (wk[i] > k) k = wk[i];
        atomicMax((unsigned long long*)(wsbest + WS_BEST), k);
    }
}

// ---------------- K4: gather active kernels (fused row-list rebuild) ------
// Each block independently rebuilds the 512-entry active-row list from
// k_idx + best bucket (ballot prefix-scan, ~2us, all blocks in parallel) --
// removes the separate k_rows launch.
__global__ __launch_bounds__(256) void k_gather(const float* __restrict__ kernels,
                                                const int* __restrict__ ws,
                                                float* __restrict__ out) {
    __shared__ int rows_s[2 * O_CH];
    __shared__ int wsum[4];
    const int tid = threadIdx.x;
    const unsigned long long key = *(const unsigned long long*)(ws + WS_BEST);
    const int bestIdx = (TSZ - 1) - (int)(key & (unsigned long long)(TSZ - 1));
    if (blockIdx.x == 0 && tid == 0) out[512 * FLATK + TSZ] = (float)bestIdx;

    for (int i = tid; i < 2 * O_CH; i += 256) rows_s[i] = -1;
    const int match = (ws[WS_KIDX + tid] == bestIdx) ? 1 : 0;
    unsigned long long m = __ballot(match);
    const int lane = tid & 63, wvi = tid >> 6;
    if (lane == 0) wsum[wvi] = __popcll(m);
    __syncthreads();   // also orders the -1 fill before the scatter
    int prefix = 0;
    for (int i = 0; i < wvi; ++i) prefix += wsum[i];
    int before = __popcll(m & ((1ull << lane) - 1ull));
    if (match) rows_s[prefix + before] = tid;
    __syncthreads();

    int gid = blockIdx.x * 256 + tid;              // 512*144 = 73728 float4s
    if (gid < 2 * O_CH * (FLATK / 4)) {
        int s = gid / (FLATK / 4);
        int j = gid - s * (FLATK / 4);
        int r = rows_s[s];
        float4 v = (r >= 0) ? *(const float4*)(kernels + r * FLATK + j * 4)
                            : make_float4(0.f, 0.f, 0.f, 0.f);
        *((float4*)out + gid) = v;
    }
}

extern "C" void kernel_launch(void* const* d_in, const int* in_sizes, int n_in,
                              void* d_out, int out_size, void* d_ws, size_t ws_size,
                              hipStream_t stream) {
    const float* input   = (const float*)d_in[0];
    const float* kernels = (const float*)d_in[1];
    const float* a       = (const float*)d_in[2];
    const float* b       = (const float*)d_in[3];
    float* out = (float*)d_out;
    int*   ws  = (int*)d_ws;

    k_init<<<96, 256, 0, stream>>>(kernels, a, b, ws);
    k_vote<<<NB * (HH / TILE_H) * 2, 512, 0, stream>>>(input, a, b, ws);
    k_argmax<<<TSZ / 256, 256, 0, stream>>>(ws, ws, out);
    k_gather<<<(2 * O_CH * (FLATK / 4) + 255) / 256, 256, 0, stream>>>(kernels, ws, out);
}